// Round 4
// baseline (1735.002 us; speedup 1.0000x reference)
//
#include <hip/hip_runtime.h>

// Seq2Seq GRU: B=256, S=128, T=64, I=63, H=1024. Inputs fp32, output fp32.
// All GEMMs: bf16 hi+lo 3-term split emulation (~fp32 accuracy).
// Encoder v9: persistent kernel, fence-free rotating buffers + register-
//   resident Whh (proven R1/R2). NEW: DUAL-RECURRENCE INTERLEAVE.
//   - Batch split into 8 groups of 32 rows. Block owns groups A=p, B=p+4
//     (same j-slice -> same weight registers). Each rotation: step A,
//     post A, step B, post B. B's compute fills A's inter-block latency
//     window (store-drain + flag + poll + L3 h-load ~6us) and vice versa.
//   - h stored as separate hi/lo planes (R3's packing put 12 VALU ops on
//     the load->MFMA critical path; reverted).
//   - MFMAs interleaved across r/z/n accumulators (3 indep dep chains).
//   - Split red buffers (redA/redB): 2 syncthreads per rotation; epilogue
//     waves (A: 0-1, B: 2-3) run while other waves continue to next K-loop.
//   - Per-wave flag posts: each epilogue wave drains its OWN vmcnt then
//     fetch_adds; consumer target = 16 posts/step (8 blocks x 2 waves).

typedef unsigned short u16;
typedef unsigned int   u32;
typedef __attribute__((ext_vector_type(8))) short s8v;   // 8 x bf16 (4 VGPRs)
typedef __attribute__((ext_vector_type(4))) float f4v;   // MFMA acc
typedef __attribute__((ext_vector_type(4))) int  i4v;    // 16B copy unit

__device__ __forceinline__ float b2f(u16 u) {
    return __uint_as_float(((u32)u) << 16);
}
__device__ __forceinline__ u16 f2b(float f) {   // round-to-nearest-even
    u32 x = __float_as_uint(f);
    u32 r = x + 0x7fffu + ((x >> 16) & 1u);
    return (u16)(r >> 16);
}
__device__ __forceinline__ float sigf(float x) {
    return 1.0f / (1.0f + __expf(-x));
}
__device__ __forceinline__ f4v mfma16(s8v a, s8v b, f4v c) {
    return __builtin_amdgcn_mfma_f32_16x16x32_bf16(a, b, c, 0, 0, 0);
}

// ---------------------------------------------------------------------------
__global__ void zero_ws(i4v* __restrict__ p, int n) {
    int i = blockIdx.x * blockDim.x + threadIdx.x;
    if (i < n) { i4v z = {0, 0, 0, 0}; p[i] = z; }
}

// Wih (3072 x 63 fp32) -> padded (3072 x 64) hi+lo, col 63 = 0
__global__ void conv_wih_split_pad(const float* __restrict__ s,
                                   u16* __restrict__ hi, u16* __restrict__ lo) {
    int idx = blockIdx.x * blockDim.x + threadIdx.x;
    int row = idx >> 6, col = idx & 63;
    float v = (col < 63) ? s[(size_t)row * 63 + col] : 0.f;
    u16 h = f2b(v);
    hi[idx] = h;
    lo[idx] = f2b(v - b2f(h));
}

// proj_W (63 x 1024 fp32) -> padded (64 x 1024) hi+lo, row 63 = 0
__global__ void conv_pw_split_pad(const float* __restrict__ s,
                                  u16* __restrict__ hi, u16* __restrict__ lo) {
    int idx = blockIdx.x * blockDim.x + threadIdx.x;
    float v = (idx < 63 * 1024) ? s[idx] : 0.f;
    u16 h = f2b(v);
    hi[idx] = h;
    lo[idx] = f2b(v - b2f(h));
}

// ---------------------------------------------------------------------------
// Persistent encoder v9: dual-recurrence interleave.
__global__ __launch_bounds__(512, 1) void enc_persist9(
    const float* __restrict__ Whh,                 // fp32 3072 x 1024
    const u16* __restrict__ WihH, const u16* __restrict__ WihL,
    const float* __restrict__ bih, const float* __restrict__ bhh,
    const float* __restrict__ xenc,
    u16* __restrict__ hbufH, u16* __restrict__ hbufL,  // 129 x (256x1024) each
    int* __restrict__ ep)                          // 64 counters x 64B
{
    __shared__ f4v redA[8][2][3][64];  // 49.2 KB: group-A k-slice partials
    __shared__ f4v redB[8][2][3][64];  // 49.2 KB
    __shared__ u16 WisH[48 * 72];      // Wih slice (persistent)
    __shared__ u16 WisL[48 * 72];

    // one-time: drop stale lines from a previous graph replay
    __builtin_amdgcn_fence(__ATOMIC_ACQUIRE, "agent");

    const int tid  = threadIdx.x;
    const int lane = tid & 63;
    const int wave = tid >> 6;          // 0..7 : k-slice owner, k0 = wave*128
    const int lrow = lane & 15;
    const int lk8  = lane >> 4;
    // XCD-aware swizzle: bid&7 = XCD; XCD owns a 128-col j-range.
    const int bid = blockIdx.x;
    const int xcd = bid & 7;
    const int y   = bid >> 3;           // 0..31
    const int p   = y & 3;              // batch-pair id
    const int jt  = xcd * 8 + (y >> 2); // 0..63
    const int j0  = jt * 16;
    const int mtA = p;                  // rows [32p, 32p+32)
    const int mtB = p + 4;              // rows [32p+128, ...)
    const int mA  = mtA * 32;
    const int mB  = mtB * 32;

    // counters: (mt 0..7, xcd 0..7); posted by 8 blocks x 2 epilogue waves
    int* subCtrA  = ep + (mtA * 8 + xcd) * 16;
    int* subCtrB  = ep + (mtB * 8 + xcd) * 16;
    int* waveCtrA = ep + (mtA * 8 + wave) * 16;
    int* waveCtrB = ep + (mtB * 8 + wave) * 16;

    // ---- one-time: Wih slice into LDS
    if (tid < 192) {
        int wr = tid >> 2, qq = tid & 3;
        int grow = (wr >> 4) * 1024 + j0 + (wr & 15);
        const u16* wpH = WihH + (size_t)grow * 64 + qq * 16;
        const u16* wpL = WihL + (size_t)grow * 64 + qq * 16;
        *(i4v*)&WisH[wr * 72 + qq * 16]     = *(const i4v*)wpH;
        *(i4v*)&WisH[wr * 72 + qq * 16 + 8] = *(const i4v*)(wpH + 8);
        *(i4v*)&WisL[wr * 72 + qq * 16]     = *(const i4v*)wpL;
        *(i4v*)&WisL[wr * 72 + qq * 16 + 8] = *(const i4v*)(wpL + 8);
    }

    // ---- one-time: this wave's Whh K-slice fp32 -> bf16 hi+lo in registers
    s8v bHf[3][4], bLf[3][4];
    const int k0 = wave * 128;
    #pragma unroll
    for (int gg = 0; gg < 3; ++gg)
        #pragma unroll
        for (int ks = 0; ks < 4; ++ks) {
            const float* ptr = Whh + (size_t)(gg * 1024 + j0 + lrow) * 1024 +
                               k0 + ks * 32 + lk8 * 8;
            f4v a = *(const f4v*)ptr;
            f4v b = *(const f4v*)(ptr + 4);
            union { u16 a[8]; s8v v; } H, L;
            #pragma unroll
            for (int j = 0; j < 8; ++j) {
                float v = (j < 4) ? a[j] : b[j - 4];
                u16 hh = f2b(v);
                H.a[j] = hh;
                L.a[j] = f2b(v - b2f(hh));
            }
            bHf[gg][ks] = H.v;
            bLf[gg][ks] = L.v;
        }

    const int jcol = j0 + lrow;
    const float bhr = bhh[jcol], bhz = bhh[1024 + jcol], bhn = bhh[2048 + jcol];
    const float bir = bih[jcol], biz = bih[1024 + jcol], bin = bih[2048 + jcol];

    // A-load element offsets (u16 elems), 2 m-tiles per group
    size_t aoffA[2], aoffB[2];
    #pragma unroll
    for (int t = 0; t < 2; ++t) {
        aoffA[t] = (size_t)(mA + t * 16 + lrow) * 1024 + k0 + lk8 * 8;
        aoffB[t] = (size_t)(mB + t * 16 + lrow) * 1024 + k0 + lk8 * 8;
    }

    // gi / epilogue ownership: wave 0,1 -> group A mtile 0,1;
    //                          wave 2,3 -> group B mtile 0,1.
    const int egrp = (wave >> 1) & 1;               // 0=A, 1=B (waves 0-3)
    const int wl   = wave & 1;                      // mtile within group
    const int myM  = (egrp ? mB : mA) + wl * 16;
    const float* xrow = xenc + (size_t)(myM + lrow) * 8064;
    float hprev[4] = {0.f, 0.f, 0.f, 0.f};

    float xf[16];
    if (wave < 4) {
        #pragma unroll
        for (int ks = 0; ks < 2; ++ks)
            #pragma unroll
            for (int j = 0; j < 8; ++j) {
                int col = ks * 32 + lk8 * 8 + j;
                xf[ks * 8 + j] = (col < 63) ? xrow[col] : 0.f;
            }
    }

    __syncthreads();   // Wis ready

    for (int s = 0; s < 128; ++s) {
        const u16* hinH = hbufH + (size_t)s * 262144;
        const u16* hinL = hbufL + (size_t)s * 262144;
        u16* houtH = hbufH + (size_t)(s + 1) * 262144;
        u16* houtL = hbufL + (size_t)(s + 1) * 262144;

        // ---- gi (waves 0-3, own group/mtile): h-independent, in wait shadow
        f4v gi_r = {0.f, 0.f, 0.f, 0.f};
        f4v gi_z = {0.f, 0.f, 0.f, 0.f};
        f4v gi_n = {0.f, 0.f, 0.f, 0.f};
        if (wave < 4) {
            #pragma unroll
            for (int ks = 0; ks < 2; ++ks) {
                union { u16 a[8]; s8v v; } xh, xl;
                #pragma unroll
                for (int j = 0; j < 8; ++j) {
                    float v = xf[ks * 8 + j];
                    u16 hh = f2b(v);
                    xh.a[j] = hh;
                    xl.a[j] = f2b(v - b2f(hh));
                }
                int ao = ks * 32 + lk8 * 8;
                s8v brh = *(const s8v*)&WisH[(lrow) * 72 + ao];
                s8v brl = *(const s8v*)&WisL[(lrow) * 72 + ao];
                s8v bzh = *(const s8v*)&WisH[(16 + lrow) * 72 + ao];
                s8v bzl = *(const s8v*)&WisL[(16 + lrow) * 72 + ao];
                s8v bnh = *(const s8v*)&WisH[(32 + lrow) * 72 + ao];
                s8v bnl = *(const s8v*)&WisL[(32 + lrow) * 72 + ao];
                gi_r = mfma16(xh.v, brh, gi_r);
                gi_z = mfma16(xh.v, bzh, gi_z);
                gi_n = mfma16(xh.v, bnh, gi_n);
                gi_r = mfma16(xh.v, brl, gi_r);
                gi_z = mfma16(xh.v, bzl, gi_z);
                gi_n = mfma16(xh.v, bnl, gi_n);
                gi_r = mfma16(xl.v, brh, gi_r);
                gi_z = mfma16(xl.v, bzh, gi_z);
                gi_n = mfma16(xl.v, bnh, gi_n);
            }
        }

        // ================= GROUP A =================
        if (s) {
            const int tgt = 16 * s;
            while (__hip_atomic_load(waveCtrA, __ATOMIC_RELAXED,
                                     __HIP_MEMORY_SCOPE_SYSTEM) < tgt)
                __builtin_amdgcn_s_sleep(1);
        }
        {
            f4v ar[2], az[2], ah[2];
            #pragma unroll
            for (int t = 0; t < 2; ++t) {
                ar[t] = f4v{0.f, 0.f, 0.f, 0.f};
                az[t] = f4v{0.f, 0.f, 0.f, 0.f};
                ah[t] = f4v{0.f, 0.f, 0.f, 0.f};
            }
            #pragma unroll
            for (int t = 0; t < 2; ++t)
                #pragma unroll
                for (int ks = 0; ks < 4; ++ks) {
                    s8v ahi = *(const s8v*)(hinH + aoffA[t] + ks * 32);
                    s8v alo = *(const s8v*)(hinL + aoffA[t] + ks * 32);
                    ar[t] = mfma16(ahi, bHf[0][ks], ar[t]);
                    az[t] = mfma16(ahi, bHf[1][ks], az[t]);
                    ah[t] = mfma16(ahi, bHf[2][ks], ah[t]);
                    ar[t] = mfma16(ahi, bLf[0][ks], ar[t]);
                    az[t] = mfma16(ahi, bLf[1][ks], az[t]);
                    ah[t] = mfma16(ahi, bLf[2][ks], ah[t]);
                    ar[t] = mfma16(alo, bHf[0][ks], ar[t]);
                    az[t] = mfma16(alo, bHf[1][ks], az[t]);
                    ah[t] = mfma16(alo, bHf[2][ks], ah[t]);
                }
            #pragma unroll
            for (int t = 0; t < 2; ++t) {
                redA[wave][t][0][lane] = ar[t];
                redA[wave][t][1][lane] = az[t];
                redA[wave][t][2][lane] = ah[t];
            }
        }
        __syncthreads();   // sync1: redA complete

        // ---- A epilogue (waves 0-1) while others go to B
        if (wave < 2) {
            f4v sr = {0.f, 0.f, 0.f, 0.f};
            f4v sz = {0.f, 0.f, 0.f, 0.f};
            f4v sh = {0.f, 0.f, 0.f, 0.f};
            #pragma unroll
            for (int w = 0; w < 8; ++w) {
                sr += redA[w][wl][0][lane];
                sz += redA[w][wl][1][lane];
                sh += redA[w][wl][2][lane];
            }
            #pragma unroll
            for (int reg = 0; reg < 4; ++reg) {
                int brow = mA + wl * 16 + lk8 * 4 + reg;
                float rr = sigf(sr[reg] + gi_r[reg] + bir + bhr);
                float zz = sigf(sz[reg] + gi_z[reg] + biz + bhz);
                float nn = tanhf(gi_n[reg] + bin + rr * (sh[reg] + bhn));
                float h = (1.f - zz) * nn + zz * hprev[reg];
                u16 hh = f2b(h);
                u16 ll = f2b(h - b2f(hh));
                hprev[reg] = b2f(hh) + b2f(ll);
                size_t off = (size_t)brow * 1024 + jcol;
                __hip_atomic_store(&houtH[off], hh, __ATOMIC_RELAXED,
                                   __HIP_MEMORY_SCOPE_SYSTEM);
                __hip_atomic_store(&houtL[off], ll, __ATOMIC_RELAXED,
                                   __HIP_MEMORY_SCOPE_SYSTEM);
            }
            asm volatile("s_waitcnt vmcnt(0)" ::: "memory");
            if (lane == 0)
                __hip_atomic_fetch_add(subCtrA, 1, __ATOMIC_RELAXED,
                                       __HIP_MEMORY_SCOPE_SYSTEM);
        }

        // ================= GROUP B =================
        if (s) {
            const int tgt = 16 * s;
            while (__hip_atomic_load(waveCtrB, __ATOMIC_RELAXED,
                                     __HIP_MEMORY_SCOPE_SYSTEM) < tgt)
                __builtin_amdgcn_s_sleep(1);
        }
        {
            f4v ar[2], az[2], ah[2];
            #pragma unroll
            for (int t = 0; t < 2; ++t) {
                ar[t] = f4v{0.f, 0.f, 0.f, 0.f};
                az[t] = f4v{0.f, 0.f, 0.f, 0.f};
                ah[t] = f4v{0.f, 0.f, 0.f, 0.f};
            }
            #pragma unroll
            for (int t = 0; t < 2; ++t)
                #pragma unroll
                for (int ks = 0; ks < 4; ++ks) {
                    s8v ahi = *(const s8v*)(hinH + aoffB[t] + ks * 32);
                    s8v alo = *(const s8v*)(hinL + aoffB[t] + ks * 32);
                    ar[t] = mfma16(ahi, bHf[0][ks], ar[t]);
                    az[t] = mfma16(ahi, bHf[1][ks], az[t]);
                    ah[t] = mfma16(ahi, bHf[2][ks], ah[t]);
                    ar[t] = mfma16(ahi, bLf[0][ks], ar[t]);
                    az[t] = mfma16(ahi, bLf[1][ks], az[t]);
                    ah[t] = mfma16(ahi, bLf[2][ks], ah[t]);
                    ar[t] = mfma16(alo, bHf[0][ks], ar[t]);
                    az[t] = mfma16(alo, bHf[1][ks], az[t]);
                    ah[t] = mfma16(alo, bHf[2][ks], ah[t]);
                }
            #pragma unroll
            for (int t = 0; t < 2; ++t) {
                redB[wave][t][0][lane] = ar[t];
                redB[wave][t][1][lane] = az[t];
                redB[wave][t][2][lane] = ah[t];
            }
        }
        __syncthreads();   // sync2: redB complete

        // ---- B epilogue (waves 2-3) while others go to next A
        if (wave >= 2 && wave < 4) {
            f4v sr = {0.f, 0.f, 0.f, 0.f};
            f4v sz = {0.f, 0.f, 0.f, 0.f};
            f4v sh = {0.f, 0.f, 0.f, 0.f};
            #pragma unroll
            for (int w = 0; w < 8; ++w) {
                sr += redB[w][wl][0][lane];
                sz += redB[w][wl][1][lane];
                sh += redB[w][wl][2][lane];
            }
            #pragma unroll
            for (int reg = 0; reg < 4; ++reg) {
                int brow = mB + wl * 16 + lk8 * 4 + reg;
                float rr = sigf(sr[reg] + gi_r[reg] + bir + bhr);
                float zz = sigf(sz[reg] + gi_z[reg] + biz + bhz);
                float nn = tanhf(gi_n[reg] + bin + rr * (sh[reg] + bhn));
                float h = (1.f - zz) * nn + zz * hprev[reg];
                u16 hh = f2b(h);
                u16 ll = f2b(h - b2f(hh));
                hprev[reg] = b2f(hh) + b2f(ll);
                size_t off = (size_t)brow * 1024 + jcol;
                __hip_atomic_store(&houtH[off], hh, __ATOMIC_RELAXED,
                                   __HIP_MEMORY_SCOPE_SYSTEM);
                __hip_atomic_store(&houtL[off], ll, __ATOMIC_RELAXED,
                                   __HIP_MEMORY_SCOPE_SYSTEM);
            }
            asm volatile("s_waitcnt vmcnt(0)" ::: "memory");
            if (lane == 0)
                __hip_atomic_fetch_add(subCtrB, 1, __ATOMIC_RELAXED,
                                       __HIP_MEMORY_SCOPE_SYSTEM);
        }

        // ---- prefetch next step's x (immutable input)
        if (wave < 4) {
            int sn = (s < 127) ? s + 1 : 127;
            const float* xr = xrow + sn * 63;
            #pragma unroll
            for (int ks = 0; ks < 2; ++ks)
                #pragma unroll
                for (int j = 0; j < 8; ++j) {
                    int col = ks * 32 + lk8 * 8 + j;
                    xf[ks * 8 + j] = (col < 63) ? xr[col] : 0.f;
                }
        }
    }
}

// ---------------------------------------------------------------------------
// gh_dec = enc_h @ dec_Whh^T + dec_bhh (fp32 out). dWhh split on the fly.
__global__ __launch_bounds__(256, 1) void gru_gemm1(
    const float* __restrict__ Whh,                 // fp32 3072 x 1024
    const float* __restrict__ bhh,
    const u16* __restrict__ hinH, const u16* __restrict__ hinL,
    float* __restrict__ gh_out)
{
    __shared__ u16 WbH[48 * 264];
    __shared__ u16 WbL[48 * 264];

    const int tid  = threadIdx.x;
    const int lane = tid & 63;
    const int wave = tid >> 6;
    const int lrow = lane & 15;
    const int lk8  = lane >> 4;
    const int mt = blockIdx.x & 3;
    const int jt = blockIdx.x >> 2;
    const int m0 = mt * 64;
    const int j0 = jt * 16;

    f4v acc_r  = {0.f, 0.f, 0.f, 0.f};
    f4v acc_z  = {0.f, 0.f, 0.f, 0.f};
    f4v acc_hn = {0.f, 0.f, 0.f, 0.f};

    f4v stgA[6], stgB[6];
    #pragma unroll
    for (int i = 0; i < 6; ++i) {
        int c16 = i * 256 + tid;
        int row = c16 >> 5, p16 = c16 & 31;
        int grow = (row >> 4) * 1024 + j0 + (row & 15);
        const float* p = Whh + (size_t)grow * 1024 + p16 * 8;
        stgA[i] = *(const f4v*)p;
        stgB[i] = *(const f4v*)(p + 4);
    }
    #pragma unroll
    for (int i = 0; i < 6; ++i) {
        int c16 = i * 256 + tid;
        int row = c16 >> 5, p16 = c16 & 31;
        union { u16 a[8]; i4v v; } H, L;
        #pragma unroll
        for (int j = 0; j < 8; ++j) {
            float v = (j < 4) ? stgA[i][j] : stgB[i][j - 4];
            u16 hh = f2b(v);
            H.a[j] = hh;
            L.a[j] = f2b(v - b2f(hh));
        }
        *(i4v*)&WbH[row * 264 + p16 * 8] = H.v;
        *(i4v*)&WbL[row * 264 + p16 * 8] = L.v;
    }
    __syncthreads();

    const size_t arow = (size_t)(m0 + wave * 16 + lrow) * 1024 + lk8 * 8;
    const u16* hp = hinH + arow;
    const u16* lp = hinL + arow;

    for (int c = 0; c < 4; ++c) {
        if (c < 3) {
            #pragma unroll
            for (int i = 0; i < 6; ++i) {
                int c16 = i * 256 + tid;
                int row = c16 >> 5, p16 = c16 & 31;
                int grow = (row >> 4) * 1024 + j0 + (row & 15);
                const float* p = Whh + (size_t)grow * 1024 + (c + 1) * 256 + p16 * 8;
                stgA[i] = *(const f4v*)p;
                stgB[i] = *(const f4v*)(p + 4);
            }
        }
        #pragma unroll
        for (int ks = 0; ks < 8; ++ks) {
            int kk = c * 256 + ks * 32;
            int bo = ks * 32 + lk8 * 8;
            s8v ahi = *(const s8v*)(hp + kk);
            s8v alo = *(const s8v*)(lp + kk);
            s8v brh = *(const s8v*)&WbH[(lrow) * 264 + bo];
            s8v brl = *(const s8v*)&WbL[(lrow) * 264 + bo];
            s8v bzh = *(const s8v*)&WbH[(16 + lrow) * 264 + bo];
            s8v bzl = *(const s8v*)&WbL[(16 + lrow) * 264 + bo];
            s8v bnh = *(const s8v*)&WbH[(32 + lrow) * 264 + bo];
            s8v bnl = *(const s8v*)&WbL[(32 + lrow) * 264 + bo];
            acc_r  = mfma16(ahi, brh, acc_r);
            acc_z  = mfma16(ahi, bzh, acc_z);
            acc_hn = mfma16(ahi, bnh, acc_hn);
            acc_r  = mfma16(ahi, brl, acc_r);
            acc_z  = mfma16(ahi, bzl, acc_z);
            acc_hn = mfma16(ahi, bnl, acc_hn);
            acc_r  = mfma16(alo, brh, acc_r);
            acc_z  = mfma16(alo, bzh, acc_z);
            acc_hn = mfma16(alo, bnh, acc_hn);
        }
        __syncthreads();
        if (c < 3) {
            #pragma unroll
            for (int i = 0; i < 6; ++i) {
                int c16 = i * 256 + tid;
                int row = c16 >> 5, p16 = c16 & 31;
                union { u16 a[8]; i4v v; } H, L;
                #pragma unroll
                for (int j = 0; j < 8; ++j) {
                    float v = (j < 4) ? stgA[i][j] : stgB[i][j - 4];
                    u16 hh = f2b(v);
                    H.a[j] = hh;
                    L.a[j] = f2b(v - b2f(hh));
                }
                *(i4v*)&WbH[row * 264 + p16 * 8] = H.v;
                *(i4v*)&WbL[row * 264 + p16 * 8] = L.v;
            }
            __syncthreads();
        }
    }

    const int jcol = j0 + lrow;
    const float bhr = bhh[jcol];
    const float bhz = bhh[1024 + jcol];
    const float bhn = bhh[2048 + jcol];
    #pragma unroll
    for (int reg = 0; reg < 4; ++reg) {
        int brow = m0 + wave * 16 + lk8 * 4 + reg;
        gh_out[(size_t)brow * 3072 + jcol]        = acc_r[reg] + bhr;
        gh_out[(size_t)brow * 3072 + 1024 + jcol] = acc_z[reg] + bhz;
        gh_out[(size_t)brow * 3072 + 2048 + jcol] = acc_hn[reg] + bhn;
    }
}

// ---------------------------------------------------------------------------
// Fused decoder (enc_h as hi/lo planes)
__global__ __launch_bounds__(256, 1) void dec_fused(
    const u16* __restrict__ WihH, const u16* __restrict__ WihL,
    const float* __restrict__ bih,
    const float* __restrict__ xdec,
    const u16* __restrict__ ehi, const u16* __restrict__ elo,
    const float* __restrict__ gh,
    const u16* __restrict__ pWH, const u16* __restrict__ pWL,
    const float* __restrict__ pb,
    float* __restrict__ out)
{
    __shared__ u16 XdH[64 * 72];
    __shared__ u16 XdL[64 * 72];
    __shared__ u16 WiH_[192 * 72];
    __shared__ u16 WiL_[192 * 72];
    __shared__ u16 nsH[64 * 72];
    __shared__ u16 nsL[64 * 72];

    const int tid  = threadIdx.x;
    const int lane = tid & 63;
    const int wave = tid >> 6;
    const int lrow = lane & 15;
    const int lk8  = lane >> 4;
    const int b    = blockIdx.x;

    {
        int row = tid >> 2, q = tid & 3;
        const float* xr = xdec + (size_t)(b * 64 + row) * 63;
        #pragma unroll
        for (int ii = 0; ii < 16; ++ii) {
            int col = q * 16 + ii;
            float v = (col < 63) ? xr[col] : 0.f;
            u16 hh = f2b(v);
            XdH[row * 72 + col] = hh;
            XdL[row * 72 + col] = f2b(v - b2f(hh));
        }
    }

    f4v oacc[4];
    #pragma unroll
    for (int f = 0; f < 4; ++f) oacc[f] = f4v{0.f, 0.f, 0.f, 0.f};

    for (int j0 = 0; j0 < 1024; j0 += 64) {
        #pragma unroll
        for (int k = 0; k < 3; ++k) {
            int c = tid + k * 256;
            int r = c >> 2, qq = c & 3;
            int grow = (r >> 6) * 1024 + j0 + (r & 63);
            const u16* srcH = WihH + (size_t)grow * 64 + qq * 16;
            const u16* srcL = WihL + (size_t)grow * 64 + qq * 16;
            *(i4v*)&WiH_[r * 72 + qq * 16]     = *(const i4v*)srcH;
            *(i4v*)&WiH_[r * 72 + qq * 16 + 8] = *(const i4v*)(srcH + 8);
            *(i4v*)&WiL_[r * 72 + qq * 16]     = *(const i4v*)srcL;
            *(i4v*)&WiL_[r * 72 + qq * 16 + 8] = *(const i4v*)(srcL + 8);
        }
        __syncthreads();

        f4v ar[4], az[4], an[4];
        #pragma unroll
        for (int jf = 0; jf < 4; ++jf) {
            ar[jf] = f4v{0.f, 0.f, 0.f, 0.f};
            az[jf] = f4v{0.f, 0.f, 0.f, 0.f};
            an[jf] = f4v{0.f, 0.f, 0.f, 0.f};
        }
        #pragma unroll
        for (int ks = 0; ks < 2; ++ks) {
            int ao = ks * 32 + lk8 * 8;
            s8v ah = *(const s8v*)&XdH[(wave * 16 + lrow) * 72 + ao];
            s8v al = *(const s8v*)&XdL[(wave * 16 + lrow) * 72 + ao];
            #pragma unroll
            for (int jf = 0; jf < 4; ++jf) {
                s8v brh = *(const s8v*)&WiH_[(jf * 16 + lrow) * 72 + ao];
                s8v brl = *(const s8v*)&WiL_[(jf * 16 + lrow) * 72 + ao];
                s8v bzh = *(const s8v*)&WiH_[(64 + jf * 16 + lrow) * 72 + ao];
                s8v bzl = *(const s8v*)&WiL_[(64 + jf * 16 + lrow) * 72 + ao];
                s8v bnh = *(const s8v*)&WiH_[(128 + jf * 16 + lrow) * 72 + ao];
                s8v bnl = *(const s8v*)&WiL_[(128 + jf * 16 + lrow) * 72 + ao];
                ar[jf] = mfma16(ah, brh, ar[jf]);
                az[jf] = mfma16(ah, bzh, az[jf]);
                an[jf] = mfma16(ah, bnh, an[jf]);
                ar[jf] = mfma16(ah, brl, ar[jf]);
                az[jf] = mfma16(ah, bzl, az[jf]);
                an[jf] = mfma16(ah, bnl, an[jf]);
                ar[jf] = mfma16(al, brh, ar[jf]);
                az[jf] = mfma16(al, bzh, az[jf]);
                an[jf] = mfma16(al, bnh, an[jf]);
            }
        }

        #pragma unroll
        for (int jf = 0; jf < 4; ++jf) {
            int j = j0 + jf * 16 + lrow;
            float ghr = gh[(size_t)b * 3072 + j];
            float ghz = gh[(size_t)b * 3072 + 1024 + j];
            float ghn = gh[(size_t)b * 3072 + 2048 + j];
            float bir = bih[j];
            float biz = bih[1024 + j];
            float bin = bih[2048 + j];
            size_t eo = (size_t)b * 1024 + j;
            float he = b2f(ehi[eo]) + b2f(elo[eo]);
            #pragma unroll
            for (int reg = 0; reg < 4; ++reg) {
                float r  = sigf(ar[jf][reg] + bir + ghr);
                float z  = sigf(az[jf][reg] + biz + ghz);
                float nn = tanhf(an[jf][reg] + bin + r * ghn);
                float v  = (1.f - z) * nn + z * he;
                u16 hh = f2b(v);
                int lo_i = (wave * 16 + lk8 * 4 + reg) * 72 + jf * 16 + lrow;
                nsH[lo_i] = hh;
                nsL[lo_i] = f2b(v - b2f(hh));
            }
        }
        __syncthreads();

        #pragma unroll
        for (int ks = 0; ks < 2; ++ks) {
            int ao = ks * 32 + lk8 * 8;
            s8v ah = *(const s8v*)&nsH[(wave * 16 + lrow) * 72 + ao];
            s8v al = *(const s8v*)&nsL[(wave * 16 + lrow) * 72 + ao];
            #pragma unroll
            for (int f = 0; f < 4; ++f) {
                size_t bo = (size_t)(f * 16 + lrow) * 1024 + j0 + ks * 32 + lk8 * 8;
                s8v bh = *(const s8v*)(pWH + bo);
                s8v bl = *(const s8v*)(pWL + bo);
                oacc[f] = mfma16(ah, bh, oacc[f]);
                oacc[f] = mfma16(ah, bl, oacc[f]);
                oacc[f] = mfma16(al, bh, oacc[f]);
            }
        }
        __syncthreads();
    }

    #pragma unroll
    for (int f = 0; f < 4; ++f) {
        int o = f * 16 + lrow;
        if (o < 63) {
            float pbv = pb[o];
            #pragma unroll
            for (int reg = 0; reg < 4; ++reg) {
                int t = wave * 16 + lk8 * 4 + reg;
                out[((size_t)(b * 64 + t)) * 63 + o] = oacc[f][reg] + pbv;
            }
        }
    }
}

// ---------------------------------------------------------------------------
extern "C" void kernel_launch(void* const* d_in, const int* in_sizes, int n_in,
                              void* d_out, int out_size, void* d_ws, size_t ws_size,
                              hipStream_t stream)
{
    const float* enc_x = (const float*)d_in[0];
    const float* dec_x = (const float*)d_in[1];
    const float* eWih  = (const float*)d_in[2];
    const float* eWhh  = (const float*)d_in[3];
    const float* ebih  = (const float*)d_in[4];
    const float* ebhh  = (const float*)d_in[5];
    const float* dWih  = (const float*)d_in[6];
    const float* dWhh  = (const float*)d_in[7];
    const float* dbih  = (const float*)d_in[8];
    const float* dbhh  = (const float*)d_in[9];
    const float* pW    = (const float*)d_in[10];
    const float* pb    = (const float*)d_in[11];

    char* ws = (char*)d_ws;

    // layout: hbufH 129x512KB | hbufL 129x512KB | ep 16KB | ghd 3MB | Wih | pW
    u16*   hbufH = (u16*)(ws);                     // 67,633,152 B
    u16*   hbufL = (u16*)(ws + 67633152);          // 67,633,152 B
    int*   ep    = (int*)(ws + 135266304);         // 16 KB counters
    float* ghd   = (float*)(ws + 135282688);       // 3 MB
    u16*   eWihH = (u16*)(ws + 138428416);         // 384 KB each
    u16*   eWihL = (u16*)(ws + 138821632);
    u16*   dWihH = (u16*)(ws + 139214848);
    u16*   dWihL = (u16*)(ws + 139608064);
    u16*   pWH   = (u16*)(ws + 140001280);         // 128 KB each
    u16*   pWL   = (u16*)(ws + 140132352);

    // small one-time conversions (Wih pad + proj pad)
    conv_wih_split_pad<<<dim3(768), dim3(256), 0, stream>>>(eWih, eWihH, eWihL);
    conv_wih_split_pad<<<dim3(768), dim3(256), 0, stream>>>(dWih, dWihH, dWihL);
    conv_pw_split_pad<<<dim3(256), dim3(256), 0, stream>>>(pW, pWH, pWL);

    // zero buf[0] (both planes) + counters
    zero_ws<<<dim3(128), dim3(256), 0, stream>>>((i4v*)hbufH, 32768);
    zero_ws<<<dim3(128), dim3(256), 0, stream>>>((i4v*)hbufL, 32768);
    zero_ws<<<dim3(4), dim3(256), 0, stream>>>((i4v*)ep, 1024);

    // persistent encoder: all 128 steps, one launch
    enc_persist9<<<dim3(256), dim3(512), 0, stream>>>(
        eWhh, eWihH, eWihL, ebih, ebhh, enc_x, hbufH, hbufL, ep);

    u16* HfinH = hbufH + (size_t)128 * 262144;     // buf[128]
    u16* HfinL = hbufL + (size_t)128 * 262144;

    // gh_dec = enc_h @ dec_Whh^T + dec_bhh (dWhh split on the fly)
    gru_gemm1<<<dim3(256), dim3(256), 0, stream>>>(dWhh, dbhh, HfinH, HfinL, ghd);

    // fused decoder gates + projection -> fp32 out
    dec_fused<<<dim3(256), dim3(256), 0, stream>>>(
        dWihH, dWihL, dbih, dec_x, HfinH, HfinL, ghd, pWH, pWL, pb,
        (float*)d_out);
}

// Round 5
// 1732.409 us; speedup vs baseline: 1.0015x; 1.0015x over previous
//
#include <hip/hip_runtime.h>

// Seq2Seq GRU: B=256, S=128, T=64, I=63, H=1024. Inputs fp32, output fp32.
// All GEMMs: bf16 hi+lo 3-term split emulation (~fp32 accuracy).
// Encoder v10: persistent kernel, 128 steps, rotating buffers (R1) +
//   register-resident Whh (R2) + packed u32 h (R3). NEW: DATA-AS-FLAG.
//   - All counters/polls/fences/drains REMOVED. Buffers 1..128 are pre-
//     filled with sentinel dwords (lo-plane = bf16 NaN 0x7FC0, unreachable:
//     the lo residual of a finite |h|<1 hi+lo split is a tiny finite bf16).
//   - Producers fire write-through system-scope packed stores and move on
//     (no vmcnt drain, no flag RMW: the store IS the signal; u32 store is
//     atomic so no torn hi/lo).
//   - Consumers load normally (L2-cached reuse when data arrived first);
//     any dword with lo==0x7FC0 is retried via L2-BYPASS loads
//     (global_load_dwordx4 sc0 sc1) until real data appears. Bypass is
//     mandatory: a premature normal load caches the sentinel line in the
//     consumer XCD's non-coherent L2.
//   - Epilogue split at the barrier: sync1 -> red reads -> sync2 ->
//     gates+stores overlapped with other waves' next (data-gated) K-loop.
//   Progression is self-gated by data: a block cannot pass step s+1 until
//   all its producers' step-s stores are visible -> skew <= 1 within an
//   mt-group; cross-launch safety via the per-launch sentinel re-fill +
//   dispatch-boundary cache invalidation (empirically proven R1-R3).

typedef unsigned short u16;
typedef unsigned int   u32;
typedef __attribute__((ext_vector_type(8))) short s8v;   // 8 x bf16 (4 VGPRs)
typedef __attribute__((ext_vector_type(4))) float f4v;   // MFMA acc
typedef __attribute__((ext_vector_type(4))) int  i4v;    // 16B copy unit
typedef __attribute__((ext_vector_type(4))) unsigned int u4v;

__device__ __forceinline__ float b2f(u16 u) {
    return __uint_as_float(((u32)u) << 16);
}
__device__ __forceinline__ u16 f2b(float f) {   // round-to-nearest-even
    u32 x = __float_as_uint(f);
    u32 r = x + 0x7fffu + ((x >> 16) & 1u);
    return (u16)(r >> 16);
}
__device__ __forceinline__ float sigf(float x) {
    return 1.0f / (1.0f + __expf(-x));
}
__device__ __forceinline__ f4v mfma16(s8v a, s8v b, f4v c) {
    return __builtin_amdgcn_mfma_f32_16x16x32_bf16(a, b, c, 0, 0, 0);
}
// 8 packed u32 (hh|ll<<16) -> hi-plane s8v + lo-plane s8v
__device__ __forceinline__ void unpack8(u4v w0, u4v w1, s8v& hi, s8v& lo) {
    u32 c0 = w0[0], c1 = w0[1], c2 = w0[2], c3 = w0[3];
    u32 c4 = w1[0], c5 = w1[1], c6 = w1[2], c7 = w1[3];
    union { u32 u[4]; s8v v; } H, L;
    H.u[0] = (c0 & 0xffffu) | (c1 << 16);
    H.u[1] = (c2 & 0xffffu) | (c3 << 16);
    H.u[2] = (c4 & 0xffffu) | (c5 << 16);
    H.u[3] = (c6 & 0xffffu) | (c7 << 16);
    L.u[0] = (c0 >> 16) | (c1 & 0xffff0000u);
    L.u[1] = (c2 >> 16) | (c3 & 0xffff0000u);
    L.u[2] = (c4 >> 16) | (c5 & 0xffff0000u);
    L.u[3] = (c6 >> 16) | (c7 & 0xffff0000u);
    hi = H.v; lo = L.v;
}

// Sentinel: lo-plane (bits 31:16) == bf16 NaN 0x7FC0 -> not yet written.
// Retry via L1+L2-bypass load (consumer L2 may hold a stale sentinel line;
// remote wt stores update MALL only -- per-XCD L2s are not coherent).
__device__ __forceinline__ u4v fix_chunk(const u32* p, u4v w) {
    while (((w[0] >> 16) == 0x7FC0u) || ((w[1] >> 16) == 0x7FC0u) ||
           ((w[2] >> 16) == 0x7FC0u) || ((w[3] >> 16) == 0x7FC0u)) {
        __builtin_amdgcn_s_sleep(2);
        unsigned long long a = (unsigned long long)p;
        asm volatile("global_load_dwordx4 %0, %1, off sc0 sc1\n\t"
                     "s_waitcnt vmcnt(0)"
                     : "=&v"(w) : "v"(a) : "memory");
    }
    return w;
}

// ---------------------------------------------------------------------------
__global__ void zero_ws(i4v* __restrict__ p, int n) {
    int i = blockIdx.x * blockDim.x + threadIdx.x;
    if (i < n) { i4v z = {0, 0, 0, 0}; p[i] = z; }
}

__global__ void fill_sent(u4v* __restrict__ p, int n) {
    int i = blockIdx.x * blockDim.x + threadIdx.x;
    int st = gridDim.x * blockDim.x;
    u4v s = {0x7FC07FC0u, 0x7FC07FC0u, 0x7FC07FC0u, 0x7FC07FC0u};
    for (; i < n; i += st) p[i] = s;
}

// Wih (3072 x 63 fp32) -> padded (3072 x 64) hi+lo, col 63 = 0
__global__ void conv_wih_split_pad(const float* __restrict__ s,
                                   u16* __restrict__ hi, u16* __restrict__ lo) {
    int idx = blockIdx.x * blockDim.x + threadIdx.x;
    int row = idx >> 6, col = idx & 63;
    float v = (col < 63) ? s[(size_t)row * 63 + col] : 0.f;
    u16 h = f2b(v);
    hi[idx] = h;
    lo[idx] = f2b(v - b2f(h));
}

// proj_W (63 x 1024 fp32) -> padded (64 x 1024) hi+lo, row 63 = 0
__global__ void conv_pw_split_pad(const float* __restrict__ s,
                                  u16* __restrict__ hi, u16* __restrict__ lo) {
    int idx = blockIdx.x * blockDim.x + threadIdx.x;
    float v = (idx < 63 * 1024) ? s[idx] : 0.f;
    u16 h = f2b(v);
    hi[idx] = h;
    lo[idx] = f2b(v - b2f(h));
}

// ---------------------------------------------------------------------------
// Persistent encoder v10: data-as-flag, no counters.
__global__ __launch_bounds__(512, 1) void enc_persist10(
    const float* __restrict__ Whh,                 // fp32 3072 x 1024
    const u16* __restrict__ WihH, const u16* __restrict__ WihL,
    const float* __restrict__ bih, const float* __restrict__ bhh,
    const float* __restrict__ xenc,
    u32* __restrict__ hbuf)                        // 129 x (256x1024) packed
{
    __shared__ f4v red[8][4][3][64];   // 98.3 KB: per-wave k-slice partials
    __shared__ u16 WisH[48 * 72];      // Wih slice (persistent)
    __shared__ u16 WisL[48 * 72];

    // one-time: drop stale lines from a previous graph replay
    __builtin_amdgcn_fence(__ATOMIC_ACQUIRE, "agent");

    const int tid  = threadIdx.x;
    const int lane = tid & 63;
    const int wave = tid >> 6;          // 0..7 : k-slice owner, k0 = wave*128
    const int lrow = lane & 15;
    const int lk8  = lane >> 4;
    // XCD-aware swizzle: bid&7 = XCD; XCD owns a 128-col j-range.
    const int bid = blockIdx.x;
    const int xcd = bid & 7;
    const int y   = bid >> 3;
    const int mt  = y & 3;
    const int jt  = xcd * 8 + (y >> 2);
    const int m0 = mt * 64;
    const int j0 = jt * 16;

    // ---- one-time: Wih slice into LDS
    if (tid < 192) {
        int wr = tid >> 2, qq = tid & 3;
        int grow = (wr >> 4) * 1024 + j0 + (wr & 15);
        const u16* wpH = WihH + (size_t)grow * 64 + qq * 16;
        const u16* wpL = WihL + (size_t)grow * 64 + qq * 16;
        *(i4v*)&WisH[wr * 72 + qq * 16]     = *(const i4v*)wpH;
        *(i4v*)&WisH[wr * 72 + qq * 16 + 8] = *(const i4v*)(wpH + 8);
        *(i4v*)&WisL[wr * 72 + qq * 16]     = *(const i4v*)wpL;
        *(i4v*)&WisL[wr * 72 + qq * 16 + 8] = *(const i4v*)(wpL + 8);
    }

    // ---- one-time: this wave's Whh K-slice fp32 -> bf16 hi+lo in registers
    s8v bHf[3][4], bLf[3][4];
    const int k0 = wave * 128;
    #pragma unroll
    for (int gg = 0; gg < 3; ++gg)
        #pragma unroll
        for (int ks = 0; ks < 4; ++ks) {
            const float* p = Whh + (size_t)(gg * 1024 + j0 + lrow) * 1024 +
                             k0 + ks * 32 + lk8 * 8;
            f4v a = *(const f4v*)p;
            f4v b = *(const f4v*)(p + 4);
            union { u16 a[8]; s8v v; } H, L;
            #pragma unroll
            for (int j = 0; j < 8; ++j) {
                float v = (j < 4) ? a[j] : b[j - 4];
                u16 hh = f2b(v);
                H.a[j] = hh;
                L.a[j] = f2b(v - b2f(hh));
            }
            bHf[gg][ks] = H.v;
            bLf[gg][ks] = L.v;
        }

    const int jcol = j0 + lrow;
    const float bhr = bhh[jcol], bhz = bhh[1024 + jcol], bhn = bhh[2048 + jcol];
    const float bir = bih[jcol], biz = bih[1024 + jcol], bin = bih[2048 + jcol];

    // A-load element offsets per m-tile (u32 elements)
    size_t aoff[4];
    #pragma unroll
    for (int mtile = 0; mtile < 4; ++mtile)
        aoff[mtile] = (size_t)(m0 + mtile * 16 + lrow) * 1024 + k0 + lk8 * 8;

    // gi / epilogue waves: wave v (0..3) owns m-tile v
    const float* xrow = xenc + (size_t)(m0 + (wave & 3) * 16 + lrow) * 8064;
    float hprev[4] = {0.f, 0.f, 0.f, 0.f};

    float xf[16];
    if (wave < 4) {
        #pragma unroll
        for (int ks = 0; ks < 2; ++ks)
            #pragma unroll
            for (int j = 0; j < 8; ++j) {
                int col = ks * 32 + lk8 * 8 + j;
                xf[ks * 8 + j] = (col < 63) ? xrow[col] : 0.f;
            }
    }

    __syncthreads();   // Wis ready

    for (int s = 0; s < 128; ++s) {
        const u32* hin = hbuf + (size_t)s * 262144;        // read buf[s]
        u32* hout      = hbuf + (size_t)(s + 1) * 262144;  // write buf[s+1]

        // ---- gi (waves 0-3): h-independent
        f4v gi_r = {0.f, 0.f, 0.f, 0.f};
        f4v gi_z = {0.f, 0.f, 0.f, 0.f};
        f4v gi_n = {0.f, 0.f, 0.f, 0.f};
        if (wave < 4) {
            #pragma unroll
            for (int ks = 0; ks < 2; ++ks) {
                union { u16 a[8]; s8v v; } xh, xl;
                #pragma unroll
                for (int j = 0; j < 8; ++j) {
                    float v = xf[ks * 8 + j];
                    u16 hh = f2b(v);
                    xh.a[j] = hh;
                    xl.a[j] = f2b(v - b2f(hh));
                }
                int ao = ks * 32 + lk8 * 8;
                s8v brh = *(const s8v*)&WisH[(lrow) * 72 + ao];
                s8v brl = *(const s8v*)&WisL[(lrow) * 72 + ao];
                s8v bzh = *(const s8v*)&WisH[(16 + lrow) * 72 + ao];
                s8v bzl = *(const s8v*)&WisL[(16 + lrow) * 72 + ao];
                s8v bnh = *(const s8v*)&WisH[(32 + lrow) * 72 + ao];
                s8v bnl = *(const s8v*)&WisL[(32 + lrow) * 72 + ao];
                gi_r = mfma16(xh.v, brh, gi_r);
                gi_z = mfma16(xh.v, bzh, gi_z);
                gi_n = mfma16(xh.v, bnh, gi_n);
                gi_r = mfma16(xh.v, brl, gi_r);
                gi_z = mfma16(xh.v, bzl, gi_z);
                gi_n = mfma16(xh.v, bnl, gi_n);
                gi_r = mfma16(xl.v, brh, gi_r);
                gi_z = mfma16(xl.v, bzh, gi_z);
                gi_n = mfma16(xl.v, bnh, gi_n);
            }
        }

        // ---- K loop: data-gated loads (sentinel retry), B in regs
        f4v accr[4], accz[4], acchn[4];
        #pragma unroll
        for (int m = 0; m < 4; ++m) {
            accr[m]  = f4v{0.f, 0.f, 0.f, 0.f};
            accz[m]  = f4v{0.f, 0.f, 0.f, 0.f};
            acchn[m] = f4v{0.f, 0.f, 0.f, 0.f};
        }
        #pragma unroll
        for (int mtile = 0; mtile < 4; ++mtile) {
            #pragma unroll
            for (int ks = 0; ks < 4; ++ks) {
                const u32* p = hin + aoff[mtile] + ks * 32;
                u4v w0 = *(const u4v*)p;
                u4v w1 = *(const u4v*)(p + 4);
                w0 = fix_chunk(p, w0);
                w1 = fix_chunk(p + 4, w1);
                s8v ahi, alo;
                unpack8(w0, w1, ahi, alo);
                accr[mtile]  = mfma16(ahi, bHf[0][ks], accr[mtile]);
                accz[mtile]  = mfma16(ahi, bHf[1][ks], accz[mtile]);
                acchn[mtile] = mfma16(ahi, bHf[2][ks], acchn[mtile]);
                accr[mtile]  = mfma16(ahi, bLf[0][ks], accr[mtile]);
                accz[mtile]  = mfma16(ahi, bLf[1][ks], accz[mtile]);
                acchn[mtile] = mfma16(ahi, bLf[2][ks], acchn[mtile]);
                accr[mtile]  = mfma16(alo, bHf[0][ks], accr[mtile]);
                accz[mtile]  = mfma16(alo, bHf[1][ks], accz[mtile]);
                acchn[mtile] = mfma16(alo, bHf[2][ks], acchn[mtile]);
            }
        }

        // ---- write k-slice partials
        #pragma unroll
        for (int m = 0; m < 4; ++m) {
            red[wave][m][0][lane] = accr[m];
            red[wave][m][1][lane] = accz[m];
            red[wave][m][2][lane] = acchn[m];
        }
        __syncthreads();   // sync1: red ready

        // ---- epilogue head (waves 0-3): ONLY the red reads before sync2
        f4v sr = {0.f, 0.f, 0.f, 0.f};
        f4v sz = {0.f, 0.f, 0.f, 0.f};
        f4v sh = {0.f, 0.f, 0.f, 0.f};
        if (wave < 4) {
            #pragma unroll
            for (int w = 0; w < 8; ++w) {
                sr += red[w][wave][0][lane];
                sz += red[w][wave][1][lane];
                sh += red[w][wave][2][lane];
            }
        }
        __syncthreads();   // sync2: red consumed; waves 4-7 proceed to next
                           // step's (data-gated) K-loop while epilogue tail
                           // and stores run concurrently below.

        // ---- epilogue tail (waves 0-3): gates + fire-and-forget wt stores
        if (wave < 4) {
            #pragma unroll
            for (int reg = 0; reg < 4; ++reg) {
                int brow = m0 + wave * 16 + lk8 * 4 + reg;
                float rr = sigf(sr[reg] + gi_r[reg] + bir + bhr);
                float zz = sigf(sz[reg] + gi_z[reg] + biz + bhz);
                float nn = tanhf(gi_n[reg] + bin + rr * (sh[reg] + bhn));
                float h = (1.f - zz) * nn + zz * hprev[reg];
                u16 hh = f2b(h);
                u16 ll = f2b(h - b2f(hh));
                hprev[reg] = b2f(hh) + b2f(ll);
                u32 pk = (u32)hh | ((u32)ll << 16);
                // write-through system store: THE STORE IS THE FLAG.
                __hip_atomic_store(&hout[(size_t)brow * 1024 + jcol], pk,
                                   __ATOMIC_RELAXED, __HIP_MEMORY_SCOPE_SYSTEM);
            }
            // prefetch next step's x (immutable input)
            int sn = (s < 127) ? s + 1 : 127;
            const float* xr = xrow + sn * 63;
            #pragma unroll
            for (int ks = 0; ks < 2; ++ks)
                #pragma unroll
                for (int j = 0; j < 8; ++j) {
                    int col = ks * 32 + lk8 * 8 + j;
                    xf[ks * 8 + j] = (col < 63) ? xr[col] : 0.f;
                }
        }
    }
}

// ---------------------------------------------------------------------------
// gh_dec = enc_h @ dec_Whh^T + dec_bhh (fp32 out). dWhh split on the fly.
__global__ __launch_bounds__(256, 1) void gru_gemm1(
    const float* __restrict__ Whh,                 // fp32 3072 x 1024
    const float* __restrict__ bhh,
    const u32* __restrict__ hin,                   // packed hh|ll<<16
    float* __restrict__ gh_out)
{
    __shared__ u16 WbH[48 * 264];
    __shared__ u16 WbL[48 * 264];

    const int tid  = threadIdx.x;
    const int lane = tid & 63;
    const int wave = tid >> 6;
    const int lrow = lane & 15;
    const int lk8  = lane >> 4;
    const int mt = blockIdx.x & 3;
    const int jt = blockIdx.x >> 2;
    const int m0 = mt * 64;
    const int j0 = jt * 16;

    f4v acc_r  = {0.f, 0.f, 0.f, 0.f};
    f4v acc_z  = {0.f, 0.f, 0.f, 0.f};
    f4v acc_hn = {0.f, 0.f, 0.f, 0.f};

    f4v stgA[6], stgB[6];
    #pragma unroll
    for (int i = 0; i < 6; ++i) {
        int c16 = i * 256 + tid;
        int row = c16 >> 5, p16 = c16 & 31;
        int grow = (row >> 4) * 1024 + j0 + (row & 15);
        const float* p = Whh + (size_t)grow * 1024 + p16 * 8;
        stgA[i] = *(const f4v*)p;
        stgB[i] = *(const f4v*)(p + 4);
    }
    #pragma unroll
    for (int i = 0; i < 6; ++i) {
        int c16 = i * 256 + tid;
        int row = c16 >> 5, p16 = c16 & 31;
        union { u16 a[8]; i4v v; } H, L;
        #pragma unroll
        for (int j = 0; j < 8; ++j) {
            float v = (j < 4) ? stgA[i][j] : stgB[i][j - 4];
            u16 hh = f2b(v);
            H.a[j] = hh;
            L.a[j] = f2b(v - b2f(hh));
        }
        *(i4v*)&WbH[row * 264 + p16 * 8] = H.v;
        *(i4v*)&WbL[row * 264 + p16 * 8] = L.v;
    }
    __syncthreads();

    const size_t arow = (size_t)(m0 + wave * 16 + lrow) * 1024 + lk8 * 8;
    const u32* hp = hin + arow;

    for (int c = 0; c < 4; ++c) {
        if (c < 3) {
            #pragma unroll
            for (int i = 0; i < 6; ++i) {
                int c16 = i * 256 + tid;
                int row = c16 >> 5, p16 = c16 & 31;
                int grow = (row >> 4) * 1024 + j0 + (row & 15);
                const float* p = Whh + (size_t)grow * 1024 + (c + 1) * 256 + p16 * 8;
                stgA[i] = *(const f4v*)p;
                stgB[i] = *(const f4v*)(p + 4);
            }
        }
        #pragma unroll
        for (int ks = 0; ks < 8; ++ks) {
            int kk = c * 256 + ks * 32;
            int bo = ks * 32 + lk8 * 8;
            u4v w0 = *(const u4v*)(hp + kk);
            u4v w1 = *(const u4v*)(hp + kk + 4);
            s8v ahi, alo;
            unpack8(w0, w1, ahi, alo);
            s8v brh = *(const s8v*)&WbH[(lrow) * 264 + bo];
            s8v brl = *(const s8v*)&WbL[(lrow) * 264 + bo];
            s8v bzh = *(const s8v*)&WbH[(16 + lrow) * 264 + bo];
            s8v bzl = *(const s8v*)&WbL[(16 + lrow) * 264 + bo];
            s8v bnh = *(const s8v*)&WbH[(32 + lrow) * 264 + bo];
            s8v bnl = *(const s8v*)&WbL[(32 + lrow) * 264 + bo];
            acc_r  = mfma16(ahi, brh, acc_r);
            acc_z  = mfma16(ahi, bzh, acc_z);
            acc_hn = mfma16(ahi, bnh, acc_hn);
            acc_r  = mfma16(ahi, brl, acc_r);
            acc_z  = mfma16(ahi, bzl, acc_z);
            acc_hn = mfma16(ahi, bnl, acc_hn);
            acc_r  = mfma16(alo, brh, acc_r);
            acc_z  = mfma16(alo, bzh, acc_z);
            acc_hn = mfma16(alo, bnh, acc_hn);
        }
        __syncthreads();
        if (c < 3) {
            #pragma unroll
            for (int i = 0; i < 6; ++i) {
                int c16 = i * 256 + tid;
                int row = c16 >> 5, p16 = c16 & 31;
                union { u16 a[8]; i4v v; } H, L;
                #pragma unroll
                for (int j = 0; j < 8; ++j) {
                    float v = (j < 4) ? stgA[i][j] : stgB[i][j - 4];
                    u16 hh = f2b(v);
                    H.a[j] = hh;
                    L.a[j] = f2b(v - b2f(hh));
                }
                *(i4v*)&WbH[row * 264 + p16 * 8] = H.v;
                *(i4v*)&WbL[row * 264 + p16 * 8] = L.v;
            }
            __syncthreads();
        }
    }

    const int jcol = j0 + lrow;
    const float bhr = bhh[jcol];
    const float bhz = bhh[1024 + jcol];
    const float bhn = bhh[2048 + jcol];
    #pragma unroll
    for (int reg = 0; reg < 4; ++reg) {
        int brow = m0 + wave * 16 + lk8 * 4 + reg;
        gh_out[(size_t)brow * 3072 + jcol]        = acc_r[reg] + bhr;
        gh_out[(size_t)brow * 3072 + 1024 + jcol] = acc_z[reg] + bhz;
        gh_out[(size_t)brow * 3072 + 2048 + jcol] = acc_hn[reg] + bhn;
    }
}

// ---------------------------------------------------------------------------
// Fused decoder (enc_h packed u32)
__global__ __launch_bounds__(256, 1) void dec_fused(
    const u16* __restrict__ WihH, const u16* __restrict__ WihL,
    const float* __restrict__ bih,
    const float* __restrict__ xdec,
    const u32* __restrict__ e32,
    const float* __restrict__ gh,
    const u16* __restrict__ pWH, const u16* __restrict__ pWL,
    const float* __restrict__ pb,
    float* __restrict__ out)
{
    __shared__ u16 XdH[64 * 72];
    __shared__ u16 XdL[64 * 72];
    __shared__ u16 WiH_[192 * 72];
    __shared__ u16 WiL_[192 * 72];
    __shared__ u16 nsH[64 * 72];
    __shared__ u16 nsL[64 * 72];

    const int tid  = threadIdx.x;
    const int lane = tid & 63;
    const int wave = tid >> 6;
    const int lrow = lane & 15;
    const int lk8  = lane >> 4;
    const int b    = blockIdx.x;

    {
        int row = tid >> 2, q = tid & 3;
        const float* xr = xdec + (size_t)(b * 64 + row) * 63;
        #pragma unroll
        for (int ii = 0; ii < 16; ++ii) {
            int col = q * 16 + ii;
            float v = (col < 63) ? xr[col] : 0.f;
            u16 hh = f2b(v);
            XdH[row * 72 + col] = hh;
            XdL[row * 72 + col] = f2b(v - b2f(hh));
        }
    }

    f4v oacc[4];
    #pragma unroll
    for (int f = 0; f < 4; ++f) oacc[f] = f4v{0.f, 0.f, 0.f, 0.f};

    for (int j0 = 0; j0 < 1024; j0 += 64) {
        #pragma unroll
        for (int k = 0; k < 3; ++k) {
            int c = tid + k * 256;
            int r = c >> 2, qq = c & 3;
            int grow = (r >> 6) * 1024 + j0 + (r & 63);
            const u16* srcH = WihH + (size_t)grow * 64 + qq * 16;
            const u16* srcL = WihL + (size_t)grow * 64 + qq * 16;
            *(i4v*)&WiH_[r * 72 + qq * 16]     = *(const i4v*)srcH;
            *(i4v*)&WiH_[r * 72 + qq * 16 + 8] = *(const i4v*)(srcH + 8);
            *(i4v*)&WiL_[r * 72 + qq * 16]     = *(const i4v*)srcL;
            *(i4v*)&WiL_[r * 72 + qq * 16 + 8] = *(const i4v*)(srcL + 8);
        }
        __syncthreads();

        f4v ar[4], az[4], an[4];
        #pragma unroll
        for (int jf = 0; jf < 4; ++jf) {
            ar[jf] = f4v{0.f, 0.f, 0.f, 0.f};
            az[jf] = f4v{0.f, 0.f, 0.f, 0.f};
            an[jf] = f4v{0.f, 0.f, 0.f, 0.f};
        }
        #pragma unroll
        for (int ks = 0; ks < 2; ++ks) {
            int ao = ks * 32 + lk8 * 8;
            s8v ah = *(const s8v*)&XdH[(wave * 16 + lrow) * 72 + ao];
            s8v al = *(const s8v*)&XdL[(wave * 16 + lrow) * 72 + ao];
            #pragma unroll
            for (int jf = 0; jf < 4; ++jf) {
                s8v brh = *(const s8v*)&WiH_[(jf * 16 + lrow) * 72 + ao];
                s8v brl = *(const s8v*)&WiL_[(jf * 16 + lrow) * 72 + ao];
                s8v bzh = *(const s8v*)&WiH_[(64 + jf * 16 + lrow) * 72 + ao];
                s8v bzl = *(const s8v*)&WiL_[(64 + jf * 16 + lrow) * 72 + ao];
                s8v bnh = *(const s8v*)&WiH_[(128 + jf * 16 + lrow) * 72 + ao];
                s8v bnl = *(const s8v*)&WiL_[(128 + jf * 16 + lrow) * 72 + ao];
                ar[jf] = mfma16(ah, brh, ar[jf]);
                az[jf] = mfma16(ah, bzh, az[jf]);
                an[jf] = mfma16(ah, bnh, an[jf]);
                ar[jf] = mfma16(ah, brl, ar[jf]);
                az[jf] = mfma16(ah, bzl, az[jf]);
                an[jf] = mfma16(ah, bnl, an[jf]);
                ar[jf] = mfma16(al, brh, ar[jf]);
                az[jf] = mfma16(al, bzh, az[jf]);
                an[jf] = mfma16(al, bnh, an[jf]);
            }
        }

        #pragma unroll
        for (int jf = 0; jf < 4; ++jf) {
            int j = j0 + jf * 16 + lrow;
            float ghr = gh[(size_t)b * 3072 + j];
            float ghz = gh[(size_t)b * 3072 + 1024 + j];
            float ghn = gh[(size_t)b * 3072 + 2048 + j];
            float bir = bih[j];
            float biz = bih[1024 + j];
            float bin = bih[2048 + j];
            u32 pk = e32[(size_t)b * 1024 + j];
            float he = b2f((u16)(pk & 0xffffu)) + b2f((u16)(pk >> 16));
            #pragma unroll
            for (int reg = 0; reg < 4; ++reg) {
                float r  = sigf(ar[jf][reg] + bir + ghr);
                float z  = sigf(az[jf][reg] + biz + ghz);
                float nn = tanhf(an[jf][reg] + bin + r * ghn);
                float v  = (1.f - z) * nn + z * he;
                u16 hh = f2b(v);
                int lo_i = (wave * 16 + lk8 * 4 + reg) * 72 + jf * 16 + lrow;
                nsH[lo_i] = hh;
                nsL[lo_i] = f2b(v - b2f(hh));
            }
        }
        __syncthreads();

        #pragma unroll
        for (int ks = 0; ks < 2; ++ks) {
            int ao = ks * 32 + lk8 * 8;
            s8v ah = *(const s8v*)&nsH[(wave * 16 + lrow) * 72 + ao];
            s8v al = *(const s8v*)&nsL[(wave * 16 + lrow) * 72 + ao];
            #pragma unroll
            for (int f = 0; f < 4; ++f) {
                size_t bo = (size_t)(f * 16 + lrow) * 1024 + j0 + ks * 32 + lk8 * 8;
                s8v bh = *(const s8v*)(pWH + bo);
                s8v bl = *(const s8v*)(pWL + bo);
                oacc[f] = mfma16(ah, bh, oacc[f]);
                oacc[f] = mfma16(ah, bl, oacc[f]);
                oacc[f] = mfma16(al, bh, oacc[f]);
            }
        }
        __syncthreads();
    }

    #pragma unroll
    for (int f = 0; f < 4; ++f) {
        int o = f * 16 + lrow;
        if (o < 63) {
            float pbv = pb[o];
            #pragma unroll
            for (int reg = 0; reg < 4; ++reg) {
                int t = wave * 16 + lk8 * 4 + reg;
                out[((size_t)(b * 64 + t)) * 63 + o] = oacc[f][reg] + pbv;
            }
        }
    }
}

// ---------------------------------------------------------------------------
extern "C" void kernel_launch(void* const* d_in, const int* in_sizes, int n_in,
                              void* d_out, int out_size, void* d_ws, size_t ws_size,
                              hipStream_t stream)
{
    const float* enc_x = (const float*)d_in[0];
    const float* dec_x = (const float*)d_in[1];
    const float* eWih  = (const float*)d_in[2];
    const float* eWhh  = (const float*)d_in[3];
    const float* ebih  = (const float*)d_in[4];
    const float* ebhh  = (const float*)d_in[5];
    const float* dWih  = (const float*)d_in[6];
    const float* dWhh  = (const float*)d_in[7];
    const float* dbih  = (const float*)d_in[8];
    const float* dbhh  = (const float*)d_in[9];
    const float* pW    = (const float*)d_in[10];
    const float* pb    = (const float*)d_in[11];

    char* ws = (char*)d_ws;

    // layout: 129MB hbuf(packed) + (gap) + 3MB ghd + 4x384KB Wih + 2x128KB pW
    u32*   hbuf  = (u32*)(ws);                     // 129 x 1MB rotating packed h
    float* ghd   = (float*)(ws + 135282688);       // 3 MB
    u16*   eWihH = (u16*)(ws + 138428416);         // 384 KB each
    u16*   eWihL = (u16*)(ws + 138821632);
    u16*   dWihH = (u16*)(ws + 139214848);
    u16*   dWihL = (u16*)(ws + 139608064);
    u16*   pWH   = (u16*)(ws + 140001280);         // 128 KB each
    u16*   pWL   = (u16*)(ws + 140132352);

    // small one-time conversions (Wih pad + proj pad); Whh splits in-kernel
    conv_wih_split_pad<<<dim3(768), dim3(256), 0, stream>>>(eWih, eWihH, eWihL);
    conv_wih_split_pad<<<dim3(768), dim3(256), 0, stream>>>(dWih, dWihH, dWihL);
    conv_pw_split_pad<<<dim3(256), dim3(256), 0, stream>>>(pW, pWH, pWL);

    // buf[0] = zeros (valid data); buf[1..128] = sentinel (lo-plane NaN)
    zero_ws<<<dim3(256), dim3(256), 0, stream>>>((i4v*)hbuf, 65536);
    fill_sent<<<dim3(4096), dim3(256), 0, stream>>>(
        (u4v*)(hbuf + 262144), 8388608);

    // persistent encoder: all 128 steps, one launch, data-gated
    enc_persist10<<<dim3(256), dim3(512), 0, stream>>>(
        eWhh, eWihH, eWihL, ebih, ebhh, enc_x, hbuf);

    u32* Hfin = hbuf + (size_t)128 * 262144;       // buf[128]

    // gh_dec = enc_h @ dec_Whh^T + dec_bhh (dWhh split on the fly)
    gru_gemm1<<<dim3(256), dim3(256), 0, stream>>>(dWhh, dbhh, Hfin, ghd);

    // fused decoder gates + projection -> fp32 out
    dec_fused<<<dim3(256), dim3(256), 0, stream>>>(
        dWihH, dWihL, dbih, dec_x, Hfin, ghd, pWH, pWL, pb, (float*)d_out);
}